// Round 10
// baseline (347.821 us; speedup 1.0000x reference)
//
#include <hip/hip_runtime.h>
#include <hip/hip_bf16.h>
#include <math.h>

#define N_IMAGE 128
#define N_REG   36
#define DIM     1024
#define MAX_WORD 60
#define OT_ITERS 20
#define MARGIN_F 0.2f
#define ALPHA_F  0.1f
#define EPS_F    1e-12f

typedef short bf16x8 __attribute__((ext_vector_type(8)));
typedef float f32x4  __attribute__((ext_vector_type(4)));

// APACK[img][c][h][rt][l15][q][e8]  : per-img 49152 elems (48 rows x 1024, rows>=36 zero)
// BPACK[cap][c][h][ct][l15][q][e8]  : per-cap 65536 elems (64 rows x 1024, rows>=60 zero)
#define APACK_PER_IMG 49152
#define BPACK_PER_CAP 65536

// ---------------- helpers ----------------

__device__ __forceinline__ unsigned int pkbf2(float a, float b) {
    union { __hip_bfloat162 h2; unsigned int u; } cv;
    cv.h2 = __float22bfloat162_rn(make_float2(a, b));
    return cv.u;
}
__device__ __forceinline__ float lo16(unsigned int u) { return __int_as_float((int)(u << 16)); }
__device__ __forceinline__ float hi16(unsigned int u) { return __int_as_float((int)(u & 0xFFFF0000u)); }

#define SWZ(x, pat) __int_as_float(__builtin_amdgcn_ds_swizzle(__float_as_int(x), (pat)))
#define BPERM(a, x) __int_as_float(__builtin_amdgcn_ds_bpermute((a), __float_as_int(x)))
#define DPPADD(x, ctrl) \
    ((x) + __int_as_float(__builtin_amdgcn_update_dpp(0, __float_as_int(x), (ctrl), 0xf, 0xf, true)))

// 16-lane group sum (all 16 lanes get the sum). Pure DPP/VALU.
__device__ __forceinline__ float bfly16_sum(float x) {
    x = DPPADD(x, 0xB1);    // quad_perm ^1
    x = DPPADD(x, 0x4E);    // quad_perm ^2
    x = DPPADD(x, 0x124);   // row_ror:4
    x = DPPADD(x, 0x128);   // row_ror:8
    return x;
}
__device__ __forceinline__ float bfly64_sum(float x, int xaddr) {
    x = bfly16_sum(x);
    x += SWZ(x, 0x401F);   // ^16
    x += BPERM(xaddr, x);  // ^32
    return x;
}

// ------- fast-path: norms + fragment-order pack (+ zero d_out) -------
// Padded rows: A = 128 img x 48, B = 128 cap x 64 (pads write zeros).

__global__ void pack_norms_kernel(const float* __restrict__ im, const float* __restrict__ s,
                                  float* __restrict__ inv_im, float* __restrict__ inv_cap,
                                  float* __restrict__ out,
                                  unsigned short* __restrict__ apack,
                                  unsigned short* __restrict__ bpack) {
    if (blockIdx.x == 0 && threadIdx.x == 0) { out[0] = 0.0f; out[1] = 0.0f; }
    const int u    = blockIdx.x * 4 + (threadIdx.x >> 6);   // padded row id, < 14336
    const int lane = threadIdx.x & 63;

    const float* src; unsigned short* dstp;
    float* normDst; int normIdx; bool valid; int rowTerm; int blockStride;
    if (u < 6144) {                       // A rows
        const int img = u / 48, rr = u - img * 48;
        valid = (rr < 36);
        src   = im + (size_t)(img * 36 + (valid ? rr : 0)) * DIM;
        dstp  = apack + (size_t)img * APACK_PER_IMG;
        rowTerm = (rr >> 4) * 512 + (rr & 15) * 32;
        blockStride = 1536;               // elems per (c*2+h) block
        normDst = inv_im; normIdx = img * 36 + rr;
    } else {                              // B rows
        const int v2 = u - 6144;
        const int capi = v2 / 64, rr = v2 - capi * 64;
        valid = (rr < 60);
        src   = s + (size_t)(capi * 60 + (valid ? rr : 0)) * DIM;
        dstp  = bpack + (size_t)capi * BPACK_PER_CAP;
        rowTerm = (rr >> 4) * 512 + (rr & 15) * 32;
        blockStride = 2048;
        normDst = inv_cap; normIdx = capi * 60 + rr;
    }

    const float4* s4 = (const float4*)src;
    float accn = 0.0f;
    for (int k = lane; k < DIM / 4; k += 64) {
        float4 v = valid ? s4[k] : make_float4(0.f, 0.f, 0.f, 0.f);
        accn += v.x * v.x + v.y * v.y + v.z * v.z + v.w * v.w;
        uint2 w2; w2.x = pkbf2(v.x, v.y); w2.y = pkbf2(v.z, v.w);
        const int g = k >> 1, parity = k & 1;
        const int c = g >> 3, rem = g & 7, h = rem >> 2, qq = rem & 3;
        const size_t off = (size_t)(c * 2 + h) * blockStride + rowTerm + qq * 8 + parity * 4;
        *(uint2*)(dstp + off) = w2;       // 8B aligned (off % 4 == 0)
    }
    for (int off = 32; off; off >>= 1) accn += __shfl_down(accn, off, 64);
    if (lane == 0 && valid) normDst[normIdx] = 1.0f / (sqrtf(accn) + EPS_F);
}

// ------- slow-path norms (no pack) -------

__global__ void norms_kernel(const float* __restrict__ im, const float* __restrict__ s,
                             float* __restrict__ inv_im, float* __restrict__ inv_cap,
                             float* __restrict__ out) {
    if (blockIdx.x == 0 && threadIdx.x == 0) { out[0] = 0.0f; out[1] = 0.0f; }
    const int NIM = N_IMAGE * N_REG;     // 4608
    const int NS  = N_IMAGE * MAX_WORD;  // 7680
    int row  = blockIdx.x * 4 + (threadIdx.x >> 6);
    int lane = threadIdx.x & 63;
    if (row >= NIM + NS) return;
    const bool isim = (row < NIM);
    const float* base = isim ? (im + (size_t)row * DIM)
                             : (s  + (size_t)(row - NIM) * DIM);
    const float4* b4 = (const float4*)base;
    float acc = 0.0f;
    for (int k = lane; k < DIM / 4; k += 64) {
        float4 v = b4[k];
        acc += v.x * v.x + v.y * v.y + v.z * v.z + v.w * v.w;
    }
    for (int off = 32; off; off >>= 1) acc += __shfl_down(acc, off, 64);
    if (lane == 0) {
        float inv = 1.0f / (sqrtf(acc) + EPS_F);
        if (isim) inv_im[row] = inv;
        else      inv_cap[row - NIM] = inv;
    }
}

// ---------------- shared OT tail (C-layout, register-resident) ----------------
// acc[rt*CT+ct][p] = M[r][w], r = rt*16 + q*4 + p, w = ct*16 + l15.

template <int CT>
__device__ __forceinline__ void ot_tail(
    f32x4* acc, const float* invImS, const float* invCapS,
    int cap, int b0, int m,
    float* __restrict__ S, float* __restrict__ SOT) {

    const int tid  = threadIdx.x;
    const int lane = tid & 63;
    const int wv   = tid >> 6;
    const int q    = lane >> 4;
    const int l15  = lane & 15;
    const int xaddr = ((lane ^ 32) << 2);
    const float mf    = (float)m;
    const float inv_m = 1.0f / mf;

    constexpr int PK = (CT + 1) / 2;
    float icap[CT]; bool vw[CT];
    #pragma unroll
    for (int ct = 0; ct < CT; ++ct) {
        const int w = ct * 16 + l15;
        vw[ct]   = (w < m);
        icap[ct] = (w < 60) ? invCapS[w] : 0.0f;
    }

    float        t_[12][CT];     // t = T/sigma
    unsigned int apk[12][PK];    // A = exp(-2C), bf16-packed
    float mxv[CT];
    #pragma unroll
    for (int ct = 0; ct < CT; ++ct) mxv[ct] = -3e38f;

    #pragma unroll
    for (int j = 0; j < 12; ++j) {
        const int rt = j >> 2, p = j & 3;
        const int r  = rt * 16 + q * 4 + p;                  // < 48
        const bool rowok = (rt < 2) || (q == 0);             // r < 36
        const float iir = rowok ? invImS[wv * 36 + (r < 36 ? r : 0)] : 0.0f;
        float av[CT];
        #pragma unroll
        for (int ct = 0; ct < CT; ++ct) {
            const float Mv = acc[rt * CT + ct][p];
            mxv[ct] = fmaxf(mxv[ct], rowok ? Mv : -3e38f);
            const float cv = 1.0f - Mv * iir * icap[ct];     // C = 1 - cos
            const bool ok  = rowok && vw[ct];
            av[ct]    = ok ? __expf(-2.0f * cv) : 0.0f;      // A = exp(-C/beta)
            t_[j][ct] = ok ? mf : 0.0f;                      // t0 = T0/sig0 = m
        }
        #pragma unroll
        for (int pk = 0; pk < PK; ++pk)
            apk[j][pk] = pkbf2(av[2 * pk], (2 * pk + 1 < CT) ? av[2 * pk + 1] : 0.0f);
    }

    const int b = b0 + wv;
    // ---- MISA: mean_w max_r M ----
    {
        float sp = 0.0f;
        #pragma unroll
        for (int ct = 0; ct < CT; ++ct) {
            float v = mxv[ct];
            v = fmaxf(v, SWZ(v, 0x401F));
            v = fmaxf(v, BPERM(xaddr, v));
            sp += vw[ct] ? v : 0.0f;
        }
        sp = bfly64_sum(sp, xaddr);      // = 4 * sum_w colmax (q-replicated)
        if (lane == 0) S[(size_t)b * N_IMAGE + cap] = sp * inv_m * 0.25f;
    }

    // ---- IPOT: 20 iterations, DPP row-sums ----
    float sig[CT];
    #pragma unroll
    for (int ct = 0; ct < CT; ++ct) sig[ct] = vw[ct] ? inv_m : 0.0f;

    for (int it = 0; it < OT_ITERS; ++it) {
        float s2[CT];
        #pragma unroll
        for (int ct = 0; ct < CT; ++ct) s2[ct] = sig[ct] * sig[ct];
        float csum[CT];
        #pragma unroll
        for (int ct = 0; ct < CT; ++ct) csum[ct] = 0.0f;
        #pragma unroll
        for (int j = 0; j < 12; ++j) {
            float at[CT];
            #pragma unroll
            for (int ct = 0; ct < CT; ++ct) {
                const float a = (ct & 1) ? hi16(apk[j][ct >> 1]) : lo16(apk[j][ct >> 1]);
                at[ct] = a * t_[j][ct];
            }
            float u = at[0] * s2[0];
            #pragma unroll
            for (int ct = 1; ct < CT; ++ct) u = fmaf(at[ct], s2[ct], u);
            float R  = bfly16_sum(u);                        // row-sum: Σ_w Qσ
            float dl = __builtin_amdgcn_rcpf(36.0f * R);
            if (j >= 8) dl = (q == 0) ? dl : 0.0f;           // pad-row guard (R=0 -> inf)
            #pragma unroll
            for (int ct = 0; ct < CT; ++ct) {
                const float tn = at[ct] * (dl * sig[ct]);    // t_new = δQ
                t_[j][ct] = tn;
                csum[ct] += tn;
            }
        }
        #pragma unroll
        for (int ct = 0; ct < CT; ++ct) {
            float cc = csum[ct];
            cc += SWZ(cc, 0x401F);                           // ^16 (across q)
            cc += BPERM(xaddr, cc);                          // ^32
            sig[ct] = vw[ct] ? __builtin_amdgcn_rcpf(mf * cc) : 0.0f;
        }
    }

    // ---- sims_ot = -Σ C∘T ;  C = -0.5 ln(A), T = t*sig ----
    {
        float pp = 0.0f;
        #pragma unroll
        for (int j = 0; j < 12; ++j) {
            #pragma unroll
            for (int ct = 0; ct < CT; ++ct) {
                const float a  = (ct & 1) ? hi16(apk[j][ct >> 1]) : lo16(apk[j][ct >> 1]);
                const float cv = -0.5f * __logf(fmaxf(a, 1e-30f));
                pp = fmaf(cv, t_[j][ct] * sig[ct], pp);
            }
        }
        pp = bfly64_sum(pp, xaddr);      // every cell counted once
        if (lane == 0) SOT[(size_t)b * N_IMAGE + cap] = -pp;
    }
}

// ---------------- FAST pair: fragment-packed global loads, barrier-free K-loop ----

template <int CT>
__device__ __forceinline__ void pair_body_fast(
    const unsigned short* __restrict__ apack, const unsigned short* __restrict__ bpack,
    const float* invImS, const float* invCapS,
    int cap, int b0, int m, float* __restrict__ S, float* __restrict__ SOT) {

    const int tid  = threadIdx.x;
    const int lane = tid & 63;
    const int wv   = tid >> 6;
    const int laneoff = (lane & 15) * 64 + (lane >> 4) * 16;   // l15*64 + q*16 bytes

    const char* pa = (const char*)(apack + (size_t)(b0 + wv) * APACK_PER_IMG) + laneoff;
    const char* pb = (const char*)(bpack + (size_t)cap * BPACK_PER_CAP) + laneoff;

    f32x4 acc[3 * CT];
    #pragma unroll
    for (int t = 0; t < 3 * CT; ++t) acc[t] = (f32x4){0.f, 0.f, 0.f, 0.f};

    for (int c = 0; c < 16; ++c) {
        const char* ca = pa + c * 6144;       // A chunk stride 3072 elems
        const char* cb = pb + c * 8192;       // B chunk stride 4096 elems
        bf16x8 afr[6], bfr[2 * CT];
        #pragma unroll
        for (int h = 0; h < 2; ++h) {
            #pragma unroll
            for (int rt = 0; rt < 3; ++rt)
                afr[h * 3 + rt] = *(const bf16x8*)(ca + h * 3072 + rt * 1024);
            #pragma unroll
            for (int ct = 0; ct < CT; ++ct)
                bfr[h * CT + ct] = *(const bf16x8*)(cb + h * 4096 + ct * 1024);
        }
        #pragma unroll
        for (int h = 0; h < 2; ++h) {
            #pragma unroll
            for (int rt = 0; rt < 3; ++rt) {
                #pragma unroll
                for (int ct = 0; ct < CT; ++ct)
                    acc[rt * CT + ct] = __builtin_amdgcn_mfma_f32_16x16x32_bf16(
                        afr[h * 3 + rt], bfr[h * CT + ct], acc[rt * CT + ct], 0, 0, 0);
            }
        }
    }

    ot_tail<CT>(acc, invImS, invCapS, cap, b0, m, S, SOT);
}

__global__ __launch_bounds__(256, 4)
void pair_kernel_fast(const unsigned short* __restrict__ apack,
                      const unsigned short* __restrict__ bpack,
                      const int* __restrict__ s_l,
                      const float* __restrict__ inv_im, const float* __restrict__ inv_cap,
                      float* __restrict__ S, float* __restrict__ SOT) {
    const int cap = blockIdx.x;
    const int b0  = blockIdx.y * 4;
    const int tid = threadIdx.x;

    __shared__ float invImS[144];
    __shared__ float invCapS[60];
    if (tid < 144) invImS[tid] = inv_im[b0 * 36 + tid];
    else if (tid < 204) invCapS[tid - 144] = inv_cap[cap * 60 + (tid - 144)];
    const int m = s_l[cap];              // uniform per block
    __syncthreads();

    const int CT = __builtin_amdgcn_readfirstlane((m + 15) >> 4);   // 1..4
    switch (CT) {
    case 1: pair_body_fast<1>(apack, bpack, invImS, invCapS, cap, b0, m, S, SOT); break;
    case 2: pair_body_fast<2>(apack, bpack, invImS, invCapS, cap, b0, m, S, SOT); break;
    case 3: pair_body_fast<3>(apack, bpack, invImS, invCapS, cap, b0, m, S, SOT); break;
    default: pair_body_fast<4>(apack, bpack, invImS, invCapS, cap, b0, m, S, SOT); break;
    }
}

// ---------------- SLOW pair (f32 inputs, LDS staging) — ws fallback ----------------

template <int CT>
__device__ __forceinline__ void pair_body_slow(
    const float* __restrict__ im, const float* __restrict__ s,
    char* smem, const float* invImS, const float* invCapS,
    int cap, int b0, int m,
    float* __restrict__ S, float* __restrict__ SOT) {

    const int tid  = threadIdx.x;
    const int lane = tid & 63;
    const int wv   = tid >> 6;
    const int q    = lane >> 4;
    const int l15  = lane & 15;
    const int q4   = tid & 15;
    const int row0 = tid >> 4;

    const char* sA = smem;
    const char* sB = smem + 27648;

    f32x4 acc[3 * CT];
    #pragma unroll
    for (int t = 0; t < 3 * CT; ++t) acc[t] = (f32x4){0.f, 0.f, 0.f, 0.f};

    for (int c = 0; c < 16; ++c) {
        const int col = c * 64 + q4 * 4;
        #pragma unroll
        for (int img = 0; img < 4; ++img) {
            #pragma unroll
            for (int j = 0; j < 3; ++j) {
                const int r = row0 + 16 * j;
                if (j < 2 || row0 < 4) {
                    const size_t ro = (size_t)(b0 * 36 + img * 36 + r) * DIM + col;
                    float4 v = *(const float4*)(im + ro);
                    uint2 w2; w2.x = pkbf2(v.x, v.y); w2.y = pkbf2(v.z, v.w);
                    *(uint2*)(smem + (img * 48 + r) * 144 + q4 * 8) = w2;
                }
            }
        }
        #pragma unroll
        for (int j = 0; j < CT; ++j) {
            const int r = row0 + 16 * j;
            if (CT < 4 || j < 3 || row0 < 12) {
                const size_t ro = (size_t)(cap * 60 + r) * DIM + col;
                float4 v = *(const float4*)(s + ro);
                uint2 w2; w2.x = pkbf2(v.x, v.y); w2.y = pkbf2(v.z, v.w);
                *(uint2*)(smem + (192 + r) * 144 + q4 * 8) = w2;
            }
        }
        __syncthreads();
        #pragma unroll
        for (int h = 0; h < 2; ++h) {
            bf16x8 bfr[CT];
            #pragma unroll
            for (int ct = 0; ct < CT; ++ct)
                bfr[ct] = *(const bf16x8*)(sB + (ct * 16 + l15) * 144 + h * 64 + q * 16);
            #pragma unroll
            for (int rt = 0; rt < 3; ++rt) {
                bf16x8 afr = *(const bf16x8*)(sA + (wv * 48 + rt * 16 + l15) * 144 + h * 64 + q * 16);
                #pragma unroll
                for (int ct = 0; ct < CT; ++ct)
                    acc[rt * CT + ct] = __builtin_amdgcn_mfma_f32_16x16x32_bf16(
                        afr, bfr[ct], acc[rt * CT + ct], 0, 0, 0);
            }
        }
        __syncthreads();
    }

    ot_tail<CT>(acc, invImS, invCapS, cap, b0, m, S, SOT);
}

__global__ __launch_bounds__(256, 4)
void pair_kernel_slow(const float* __restrict__ im, const float* __restrict__ s,
                      const int* __restrict__ s_l,
                      const float* __restrict__ inv_im, const float* __restrict__ inv_cap,
                      float* __restrict__ S, float* __restrict__ SOT) {
    const int cap = blockIdx.x;
    const int b0  = blockIdx.y * 4;
    const int tid = threadIdx.x;

    __shared__ __align__(16) char smem[36864];
    __shared__ float invImS[144];
    __shared__ float invCapS[60];

    if (tid < 144) invImS[tid] = inv_im[b0 * 36 + tid];
    else if (tid < 204) invCapS[tid - 144] = inv_cap[cap * 60 + (tid - 144)];
    const int m = s_l[cap];

    {   // zero staging (pad rows must be 0 for MFMA)
        float4 z = make_float4(0.f, 0.f, 0.f, 0.f);
        #pragma unroll
        for (int j = 0; j < 9; ++j)
            *(float4*)(smem + (tid + j * 256) * 16) = z;
    }
    __syncthreads();

    const int CT = __builtin_amdgcn_readfirstlane((m + 15) >> 4);
    switch (CT) {
    case 1: pair_body_slow<1>(im, s, smem, invImS, invCapS, cap, b0, m, S, SOT); break;
    case 2: pair_body_slow<2>(im, s, smem, invImS, invCapS, cap, b0, m, S, SOT); break;
    case 3: pair_body_slow<3>(im, s, smem, invImS, invCapS, cap, b0, m, S, SOT); break;
    default: pair_body_slow<4>(im, s, smem, invImS, invCapS, cap, b0, m, S, SOT); break;
    }
}

// ---------------- loss: 128 blocks, atomic accumulate ----------------

__global__ void loss_kernel(const float* __restrict__ S, const float* __restrict__ SOT,
                            float* __restrict__ out) {
    const int j = blockIdx.x;
    const int t = threadIdx.x;           // 128 threads
    __shared__ float sh[4][2];
    const float db  = S[j * 129];        // diag
    const float dob = SOT[j * 129];
    float rv = 0.f, rov = 0.f, cv = 0.f, cov = 0.f;
    if (t != j) {
        float cs  = fmaxf(0.0f, MARGIN_F + S[j * 128 + t] - db);
        float cso = fmaxf(0.0f, MARGIN_F + SOT[j * 128 + t] - dob);
        rv = cs + ALPHA_F * cso;  rov = cso;
        float ci  = fmaxf(0.0f, MARGIN_F + S[t * 128 + j] - db);
        float cio = fmaxf(0.0f, MARGIN_F + SOT[t * 128 + j] - dob);
        cv = ci + ALPHA_F * cio;  cov = cio;
    }
    for (int off = 32; off; off >>= 1) {
        rv  = fmaxf(rv,  __shfl_down(rv,  off, 64));
        rov = fmaxf(rov, __shfl_down(rov, off, 64));
        cv  = fmaxf(cv,  __shfl_down(cv,  off, 64));
        cov = fmaxf(cov, __shfl_down(cov, off, 64));
    }
    if ((t & 63) == 0) {
        sh[0][t >> 6] = rv; sh[1][t >> 6] = rov;
        sh[2][t >> 6] = cv; sh[3][t >> 6] = cov;
    }
    __syncthreads();
    if (t == 0) {
        float a0 = fmaxf(sh[0][0], sh[0][1]) + fmaxf(sh[2][0], sh[2][1]);
        float a1 = fmaxf(sh[1][0], sh[1][1]) + fmaxf(sh[3][0], sh[3][1]);
        atomicAdd(&out[0], a0);
        atomicAdd(&out[1], a1);
    }
}

extern "C" void kernel_launch(void* const* d_in, const int* in_sizes, int n_in,
                              void* d_out, int out_size, void* d_ws, size_t ws_size,
                              hipStream_t stream) {
    const float* im  = (const float*)d_in[0];
    const float* s   = (const float*)d_in[1];
    const int*   s_l = (const int*)d_in[2];
    float* out = (float*)d_out;
    float* ws  = (float*)d_ws;

    float* inv_im  = ws;
    float* inv_cap = ws + 4608;
    float* S       = ws + 12288;
    float* SOT     = ws + 12288 + 16384;
    unsigned short* apack = (unsigned short*)((char*)d_ws + 180224);
    unsigned short* bpack = apack + (size_t)N_IMAGE * APACK_PER_IMG;

    const size_t need = 180224 +
        ((size_t)N_IMAGE * APACK_PER_IMG + (size_t)N_IMAGE * BPACK_PER_CAP) * 2;
    const int fast = (ws_size >= need) ? 1 : 0;   // ws_size is call-invariant

    if (fast) {
        pack_norms_kernel<<<dim3((6144 + 8192) / 4), dim3(256), 0, stream>>>(
            im, s, inv_im, inv_cap, out, apack, bpack);
        pair_kernel_fast<<<dim3(N_IMAGE, N_IMAGE / 4), dim3(256), 0, stream>>>(
            apack, bpack, s_l, inv_im, inv_cap, S, SOT);
    } else {
        norms_kernel<<<dim3((4608 + 7680) / 4), dim3(256), 0, stream>>>(
            im, s, inv_im, inv_cap, out);
        pair_kernel_slow<<<dim3(N_IMAGE, N_IMAGE / 4), dim3(256), 0, stream>>>(
            im, s, s_l, inv_im, inv_cap, S, SOT);
    }
    loss_kernel<<<dim3(N_IMAGE), dim3(128), 0, stream>>>(S, SOT, out);
}